// Round 17
// baseline (50.765 us; speedup 1.0000x reference)
//
#include <hip/hip_runtime.h>

#define GN 192
#define GNN (GN * GN)
#define GTOT (GN * GN * GN)   // 7,077,888
#define NSLOTS 256
#define NBLK (GN * 96)        // 18432 blocks: (i, j-pair)
#define CHUNK (NBLK / 8)      // 2304  (18432 % 8 == 0 -> bijective swizzle)

typedef int   int32x4_t __attribute__((ext_vector_type(4)));
typedef float floatx4_t __attribute__((ext_vector_type(4)));
typedef float floatx2_t __attribute__((ext_vector_type(2)));
typedef float v2        __attribute__((ext_vector_type(2)));

extern "C" __device__ floatx4_t
llvm_amdgcn_raw_buffer_load_fp32x4(int32x4_t srsrc, int voffset, int soffset,
                                   int aux) __asm("llvm.amdgcn.raw.buffer.load.v4f32");
extern "C" __device__ floatx2_t
llvm_amdgcn_raw_buffer_load_fp32x2(int32x4_t srsrc, int voffset, int soffset,
                                   int aux) __asm("llvm.amdgcn.raw.buffer.load.v2f32");
extern "C" __device__ float
llvm_amdgcn_raw_buffer_load_fp32(int32x4_t srsrc, int voffset, int soffset,
                                 int aux) __asm("llvm.amdgcn.raw.buffer.load.f32");

__device__ __forceinline__ int32x4_t make_srd(const void* ptr, unsigned bytes) {
    int32x4_t r;
    unsigned long long a = (unsigned long long)ptr;
    r.x = (int)(unsigned)(a & 0xFFFFFFFFu);
    r.y = (int)(unsigned)(a >> 32);
    r.z = (int)bytes;          // OOB dwords read 0 (tail overreads safe+unused)
    r.w = 0x00020000;
    return r;
}

// Block: 192 threads = one i, two adjacent j-lines (j0,j1), full k.
// LDS: 8 u-lines, 576 dwords each:
//   0:(i,jm) 1:(i,j0) 2:(i,j1) 3:(i,jp) 4:(i-1,j0) 5:(i-1,j1) 6:(i+1,j0) 7:(i+1,j1)
__global__ __launch_bounds__(192, 4) void ns_loss_kernel(
    const float* __restrict__ u,      // (N,N,N,3)
    const float* __restrict__ uprev,  // (N,N,N,3)
    const float* __restrict__ p,      // (N,N,N)
    const float* __restrict__ rho,    // (N,N,N)
    const float* __restrict__ nu,
    const float* __restrict__ h,
    const float* __restrict__ dt,
    const float* __restrict__ grav,
    double* __restrict__ acc)
{
    __shared__ __align__(16) float ldsU[8 * 576];   // 18432 B

    const int d = blockIdx.x;
    const int o = (d & 7) * CHUNK + (d >> 3);       // XCD-chunked, bijective
    const int i   = o / 96;
    const int jpi = o % 96;
    const int j0 = 2 * jpi, j1 = j0 + 1;
    const int t = threadIdx.x;
    const int lane = t & 63;

    const int jmr = (j0 == 0)      ? GN - 1 : j0 - 1;
    const int jpr = (j1 == GN - 1) ? 0      : j1 + 1;
    const int imr = (i == 0)       ? GN - 1 : i - 1;
    const int ipr = (i == GN - 1)  ? 0      : i + 1;

    const int32x4_t srd_u  = make_srd(u,     (unsigned)GTOT * 12u);
    const int32x4_t srd_up = make_srd(uprev, (unsigned)GTOT * 12u);
    const int32x4_t srd_p  = make_srd(p,     (unsigned)GTOT * 4u);
    const int32x4_t srd_r  = make_srd(rho,   (unsigned)GTOT * 4u);

    // ---- staging: 8 lines x 2304 B; 24 threads per line, 6 x4-chunks each ----
    const int l   = t / 24;            // staged line 0..7
    const int sub = t - l * 24;        // 0..23
    int srow, scol;
    if (l < 4) { srow = i;                  scol = (l == 0) ? jmr : (l == 1) ? j0 : (l == 2) ? j1 : jpr; }
    else       { srow = (l < 6) ? imr : ipr; scol = (l & 1) ? j1 : j0; }
    const int gb = (srow * GN + scol) * GN;     // cell base of staged line

    const floatx4_t s0 = llvm_amdgcn_raw_buffer_load_fp32x4(srd_u, 12 * gb + 16 * (sub + 0),   0, 0);
    const floatx4_t s1 = llvm_amdgcn_raw_buffer_load_fp32x4(srd_u, 12 * gb + 16 * (sub + 24),  0, 0);
    const floatx4_t s2 = llvm_amdgcn_raw_buffer_load_fp32x4(srd_u, 12 * gb + 16 * (sub + 48),  0, 0);
    const floatx4_t s3 = llvm_amdgcn_raw_buffer_load_fp32x4(srd_u, 12 * gb + 16 * (sub + 72),  0, 0);
    const floatx4_t s4 = llvm_amdgcn_raw_buffer_load_fp32x4(srd_u, 12 * gb + 16 * (sub + 96),  0, 0);
    const floatx4_t s5 = llvm_amdgcn_raw_buffer_load_fp32x4(srd_u, 12 * gb + 16 * (sub + 120), 0, 0);

    // ---- own-pair indices + direct loads (fly under the staging drain) ----
    const int jj = t / 96;             // 0 -> j0, 1 -> j1
    const int mm = t - jj * 96;        // k-pair index
    const int jr = j0 + jj;
    const int k0 = 2 * mm;
    const int c0g = (i * GN + jr) * GN + k0;
    const int jrp = (jj == 0) ? j1 : jpr;
    const int jrm = (jj == 0) ? jmr : j0;

    const floatx4_t M  = llvm_amdgcn_raw_buffer_load_fp32x4(srd_up, 12 * c0g,      0, 0);
    const floatx4_t M2 = llvm_amdgcn_raw_buffer_load_fp32x4(srd_up, 12 * c0g + 16, 0, 0);
    const floatx2_t P0  = llvm_amdgcn_raw_buffer_load_fp32x2(srd_p, 4 * c0g, 0, 0);
    const floatx2_t Pip = llvm_amdgcn_raw_buffer_load_fp32x2(srd_p, 4 * ((ipr * GN + jr) * GN + k0), 0, 0);
    const floatx2_t Pim = llvm_amdgcn_raw_buffer_load_fp32x2(srd_p, 4 * ((imr * GN + jr) * GN + k0), 0, 0);
    const floatx2_t Pjp = llvm_amdgcn_raw_buffer_load_fp32x2(srd_p, 4 * ((i * GN + jrp) * GN + k0), 0, 0);
    const floatx2_t Pjm = llvm_amdgcn_raw_buffer_load_fp32x2(srd_p, 4 * ((i * GN + jrm) * GN + k0), 0, 0);
    const floatx2_t RR  = llvm_amdgcn_raw_buffer_load_fp32x2(srd_r, 4 * c0g, 0, 0);

    // ---- LDS writes (compiler inserts the vmcnt waits) ----
    {
        const int wb = l * 576 + 4 * sub;
        *(floatx4_t*)&ldsU[wb]           = s0;
        *(floatx4_t*)&ldsU[wb + 4 * 24]  = s1;
        *(floatx4_t*)&ldsU[wb + 4 * 48]  = s2;
        *(floatx4_t*)&ldsU[wb + 4 * 72]  = s3;
        *(floatx4_t*)&ldsU[wb + 4 * 96]  = s4;
        *(floatx4_t*)&ldsU[wb + 4 * 120] = s5;
    }

    // uniform scalars
    const float h0 = h[0], h1v = h[1], h2v = h[2];
    const float i2h0 = 0.5f / h0, i2h1 = 0.5f / h1v, i2h2 = 0.5f / h2v;
    const float ihs0 = 1.0f / (h0 * h0), ihs1 = 1.0f / (h1v * h1v), ihs2 = 1.0f / (h2v * h2v);
    const float invdt = 1.0f / dt[0];
    const float nu0 = nu[0];
    const float g0 = grav[0], g1v = grav[1], g2v = grav[2];
    const float s2h = 2.0f * (ihs0 + ihs1 + ihs2);

    __syncthreads();

    // ---- compute: read pair fragments from LDS (3x ds_read_b64 per line) ----
    const int lc  = 1 + jj;
    const int ljm = jj ? 1 : 0;
    const int ljp = jj ? 3 : 2;
    const int lim = 4 + jj;
    const int lip = 6 + jj;
    const int dwc = 6 * mm;

    #define RD6(L, X, Y, Z)                                              \
        v2 X, Y, Z;                                                      \
        {                                                                \
            const v2 r0 = *(const v2*)&ldsU[(L) * 576 + dwc];            \
            const v2 r1 = *(const v2*)&ldsU[(L) * 576 + dwc + 2];        \
            const v2 r2 = *(const v2*)&ldsU[(L) * 576 + dwc + 4];        \
            X = v2{r0.x, r1.y}; Y = v2{r0.y, r2.x}; Z = v2{r1.x, r2.y};  \
        }

    RD6(lc,  ucx, ucy, ucz)
    RD6(ljm, ymx, ymy, ymz)
    RD6(ljp, ypx, ypy, ypz)
    RD6(lim, xmx, xmy, xmz)
    RD6(lip, xpx, xpy, xpz)
    #undef RD6

    const float c0x = ucx.x, c0y = ucy.x, c0z = ucz.x;
    const float c1x = ucx.y, c1y = ucy.y, c1z = ucz.y;

    // ---- z-halos via intra-wave shuffles, fixups from LDS / global-p ----
    v2 zmx = {__shfl_up(c1x, 1), c0x};
    v2 zmy = {__shfl_up(c1y, 1), c0y};
    v2 zmz = {__shfl_up(c1z, 1), c0z};
    v2 zpx = {c1x, __shfl_down(c0x, 1)};
    v2 zpy = {c1y, __shfl_down(c0y, 1)};
    v2 zpz = {c1z, __shfl_down(c0z, 1)};
    v2 pzm2 = {__shfl_up((float)P0.y, 1), P0.x};
    v2 pzp2 = {P0.y, __shfl_down((float)P0.x, 1)};

    if (mm == 0 || lane == 0) {
        const int km = (k0 + GN - 1) % GN;               // cell k0-1 wrapped
        const int dw = lc * 576 + 3 * km;
        zmx.x = ldsU[dw]; zmy.x = ldsU[dw + 1]; zmz.x = ldsU[dw + 2];
        const int zmc_g = (mm == 0) ? c0g + (GN - 1) : c0g - 1;
        pzm2.x = llvm_amdgcn_raw_buffer_load_fp32(srd_p, 4 * zmc_g, 0, 0);
    }
    if (mm == 95 || lane == 63) {
        const int kp = (k0 + 2) % GN;                    // cell k1+1 wrapped
        const int dw = lc * 576 + 3 * kp;
        zpx.y = ldsU[dw]; zpy.y = ldsU[dw + 1]; zpz.y = ldsU[dw + 2];
        const int zpc_g = (mm == 95) ? c0g + 2 - GN : c0g + 2;
        pzp2.y = llvm_amdgcn_raw_buffer_load_fp32(srd_p, 4 * zpc_g, 0, 0);
    }

    const v2 upx = {M.x, M.w}, upy = {M.y, M2.x}, upz = {M.z, M2.y};

    // ---- packed stencil math (validated form) ----
    v2 dXx = (xpx - xmx) * i2h0, dXy = (xpy - xmy) * i2h0, dXz = (xpz - xmz) * i2h0;
    v2 dYx = (ypx - ymx) * i2h1, dYy = (ypy - ymy) * i2h1, dYz = (ypz - ymz) * i2h1;
    v2 dZx = (zpx - zmx) * i2h2, dZy = (zpy - zmy) * i2h2, dZz = (zpz - zmz) * i2h2;

    v2 lapx = (xpx + xmx) * ihs0 + (ypx + ymx) * ihs1 + (zpx + zmx) * ihs2 - ucx * s2h;
    v2 lapy = (xpy + xmy) * ihs0 + (ypy + ymy) * ihs1 + (zpy + zmy) * ihs2 - ucy * s2h;
    v2 lapz = (xpz + xmz) * ihs0 + (ypz + ymz) * ihs1 + (zpz + zmz) * ihs2 - ucz * s2h;

    v2 convx = ucx * dXx + ucy * dYx + ucz * dZx;
    v2 convy = ucx * dXy + ucy * dYy + ucz * dZy;
    v2 convz = ucx * dXz + ucy * dYz + ucz * dZz;

    v2 dpx = (Pip - Pim) * i2h0;
    v2 dpy = (Pjp - Pjm) * i2h1;
    v2 dpz = (pzp2 - pzm2) * i2h2;

    v2 irho;
    irho.x = __builtin_amdgcn_rcpf(RR.x + 1e-8f);
    irho.y = __builtin_amdgcn_rcpf(RR.y + 1e-8f);

    v2 Rx = (ucx - upx) * invdt + convx + dpx * irho - lapx * nu0 - g0;
    v2 Ry = (ucy - upy) * invdt + convy + dpy * irho - lapy * nu0 - g1v;
    v2 Rz = (ucz - upz) * invdt + convz + dpz * irho - lapz * nu0 - g2v;
    v2 Rc = dXx + dYy + dZz;

    v2 m2 = Rx * Rx + Ry * Ry + Rz * Rz;
    v2 c2 = Rc * Rc;
    float msum = m2.x + m2.y;
    float csum = c2.x + c2.y;

    // ---- reduce: wave(64) shuffle, 3 waves via LDS, one atomic per block ----
    #pragma unroll
    for (int off = 32; off > 0; off >>= 1) {
        msum += __shfl_down(msum, off);
        csum += __shfl_down(csum, off);
    }

    __shared__ double smom[3], scont[3];
    const int wid = t >> 6;
    if (lane == 0) { smom[wid] = (double)msum; scont[wid] = (double)csum; }
    __syncthreads();
    if (t == 0) {
        const double mmv = smom[0] + smom[1] + smom[2];
        const double ccv = scont[0] + scont[1] + scont[2];
        double* slot = acc + 2 * (blockIdx.x & (NSLOTS - 1));
        unsafeAtomicAdd(slot, mmv);
        unsafeAtomicAdd(slot + 1, ccv);
    }
}

__global__ __launch_bounds__(256) void ns_finalize_kernel(const double* __restrict__ acc,
                                                          float* __restrict__ out)
{
    const int tid = threadIdx.x;
    double mom = acc[2 * tid];
    double cont = acc[2 * tid + 1];
    #pragma unroll
    for (int off = 32; off > 0; off >>= 1) {
        mom  += __shfl_down(mom, off);
        cont += __shfl_down(cont, off);
    }
    __shared__ double smom[4], scont[4];
    const int wid = tid >> 6;
    const int lane = tid & 63;
    if (lane == 0) { smom[wid] = mom; scont[wid] = cont; }
    __syncthreads();
    if (tid == 0) {
        const double m = (smom[0] + smom[1] + smom[2] + smom[3]) / (double)GTOT;
        const double c = (scont[0] + scont[1] + scont[2] + scont[3]) / (double)GTOT;
        out[0] = (float)(m + 10.0 * c);
        out[1] = (float)m;
        out[2] = (float)c;
    }
}

extern "C" void kernel_launch(void* const* d_in, const int* in_sizes, int n_in,
                              void* d_out, int out_size, void* d_ws, size_t ws_size,
                              hipStream_t stream)
{
    const float* u     = (const float*)d_in[0];
    const float* uprev = (const float*)d_in[1];
    const float* p     = (const float*)d_in[2];
    const float* rho   = (const float*)d_in[3];
    const float* nu    = (const float*)d_in[4];
    const float* h     = (const float*)d_in[5];
    const float* dt    = (const float*)d_in[6];
    const float* grav  = (const float*)d_in[7];

    double* acc = (double*)d_ws;

    (void)hipMemsetAsync(d_ws, 0, NSLOTS * 2 * sizeof(double), stream);

    ns_loss_kernel<<<NBLK, 192, 0, stream>>>(u, uprev, p, rho, nu, h, dt, grav, acc);
    ns_finalize_kernel<<<1, 256, 0, stream>>>(acc, (float*)d_out);
}